// Round 9
// baseline (8470.970 us; speedup 1.0000x reference)
//
#include <hip/hip_runtime.h>

typedef __attribute__((ext_vector_type(8))) short short8;
typedef __attribute__((ext_vector_type(4))) float floatx4;

#define BB 2048   // batch
#define SS 24     // seq len (src and tgt)
#define HH 1024   // hidden
#define VV 37     // vocab
#define EE 256    // embed
#define G4H 4096  // 4*H gates
#define OSTR (SS * VV)   // out row stride = 888

__device__ __forceinline__ unsigned short f2bf(float f) {
    union { float f; unsigned u; } x; x.f = f;
    unsigned r = x.u + 0x7FFF + ((x.u >> 16) & 1);   // RNE
    return (unsigned short)(r >> 16);
}
__device__ __forceinline__ float bf2f(unsigned short s) {
    union { unsigned u; float f; } x; x.u = ((unsigned)s) << 16; return x.f;
}
__device__ __forceinline__ float sigm(float x) {
    x = fminf(fmaxf(x, -15.f), 15.f);
    return 1.f / (1.f + __expf(-x));
}
__device__ __forceinline__ float tanh_(float x) {
    x = fminf(fmaxf(x, -15.f), 15.f);
    float e = __expf(2.f * x);
    return (e - 1.f) / (e + 1.f);
}

// permuted W row C <- original row: gate g=(C>>4)&3 (i,f,g,o), unit u=(C>>6)*16+(C&15)
__device__ __forceinline__ int wrow_orig(int C) {
    return (((C >> 4) & 3) << 10) | ((C >> 6) << 4) | (C & 15);
}

// async global->LDS DMA, 16B/lane; LDS dest = wave-uniform base + lane*16 [m97/m104]
typedef const __attribute__((address_space(1))) void* gas_t;
typedef __attribute__((address_space(3))) void* las_t;
__device__ __forceinline__ void gl_lds16(const void* g, void* l) {
    __builtin_amdgcn_global_load_lds((gas_t)g, (las_t)l, 16, 0, 0);
}

// ---------------- fp32 -> bf16 plain conversion (fcW) ----------------
__global__ __launch_bounds__(256)
void cvt_f2b_kernel(const float* __restrict__ s, unsigned short* __restrict__ d, int n4) {
    int i = blockIdx.x * 256 + threadIdx.x;
    if (i >= n4) return;
    float4 v = reinterpret_cast<const float4*>(s)[i];
    ushort4 o;
    o.x = f2bf(v.x); o.y = f2bf(v.y); o.z = f2bf(v.z); o.w = f2bf(v.w);
    reinterpret_cast<ushort4*>(d)[i] = o;
}

// ------- fp32 -> bf16 with gate-in-16-col-group permutation (K=1024 weights) -------
__global__ __launch_bounds__(256)
void cvt_perm_kernel(const float* __restrict__ s, unsigned short* __restrict__ d) {
    int i = blockIdx.x * 256 + threadIdx.x;     // over 4096 * 256 float4 groups
    int C  = i >> 8;                            // out row 0..4095
    int kk = i & 255;
    float4 v = reinterpret_cast<const float4*>(s)[(size_t)wrow_orig(C) * 256 + kk];
    ushort4 o;
    o.x = f2bf(v.x); o.y = f2bf(v.y); o.z = f2bf(v.z); o.w = f2bf(v.w);
    reinterpret_cast<ushort4*>(d)[(size_t)i] = o;
}

// ---------------- zero init (h0a,h1a bf16 + c0,c1 fp32 region, 24 MiB) ----------------
__global__ __launch_bounds__(256) void zero16_kernel(uint4* __restrict__ p) {
    uint4 z; z.x = 0; z.y = 0; z.z = 0; z.w = 0;
    p[(size_t)blockIdx.x * 256 + threadIdx.x] = z;
}

// ---------------- token matrix [2,S,B] ----------------
__global__ __launch_bounds__(256)
void tok_kernel(const int* __restrict__ src, const int* __restrict__ tgt, int* __restrict__ toks) {
    int idx = blockIdx.x * 256 + threadIdx.x;   // 2*24*2048
    int b  = idx & 2047;
    int st = idx >> 11;
    int tok;
    if (st < SS) tok = src[b * SS + st];
    else { int t = st - SS; tok = (t == 0) ? 1 : tgt[b * SS + (t - 1)]; }
    toks[idx] = tok;
}

// ---------------- per-layer bias sums, permuted layout ----------------
__global__ __launch_bounds__(256) void bias_sum_kernel(
        const float* e0i, const float* e0h, const float* e1i, const float* e1h,
        const float* d0i, const float* d0h, const float* d1i, const float* d1h,
        float* __restrict__ out) {
    int idx = blockIdx.x * 256 + threadIdx.x;   // 4*4096
    int layer = idx >> 12, C = idx & 4095;
    int src_j = wrow_orig(C);
    const float* pi; const float* ph;
    switch (layer) {
        case 0:  pi = e0i; ph = e0h; break;
        case 1:  pi = e1i; ph = e1h; break;
        case 2:  pi = d0i; ph = d0h; break;
        default: pi = d1i; ph = d1h; break;
    }
    out[idx] = pi[src_j] + ph[src_j];
}

// ---------------- fp32 input-projection tables: proj[table][v][C] ----------------
__global__ __launch_bounds__(256)
void proj_kernel(const float* __restrict__ emb, const float* __restrict__ eWih,
                 const float* __restrict__ dWih, float* __restrict__ proj) {
    // grid = 2 tables * 37 v * 16 C-blocks = 1184
    int bid = blockIdx.x;
    int table = bid / (VV * 16);
    int rem   = bid - table * (VV * 16);
    int v     = rem >> 4;
    int cblk  = rem & 15;
    const float* W = table ? dWih : eWih;
    __shared__ float es[EE];
    es[threadIdx.x] = emb[v * EE + threadIdx.x];
    __syncthreads();
    int C = (cblk << 8) + threadIdx.x;
    const float* wr = W + (size_t)wrow_orig(C) * EE;
    float acc = 0.f;
#pragma unroll 8
    for (int k = 0; k < EE; ++k) acc += es[k] * wr[k];
    proj[((size_t)table * VV + v) * G4H + C] = acc;
}

// ---------------- LSTM step GEMM + cell: A register-direct, W via gl_lds ----------
// gates[2048,4096] = A0 @ W0^T (+ A1 @ W1^T for chunks 16..31) + bias (+ proj[tok])
// 128x128 tile, BK=64. r4 loop structure, but A fragments load STRAIGHT to VGPRs
// (16B/lane, MFMA-ready) — halves the global_load_lds DMA-path bytes (32->16 KB/chunk).
// W staged in LDS exactly as r4. In-register LSTM epilogue (no bank conflicts).
__global__ __launch_bounds__(256, 2)
void lstm_step(const unsigned short* __restrict__ A0, const unsigned short* __restrict__ W0,
               const unsigned short* __restrict__ A1, const unsigned short* __restrict__ W1,
               int nchunk,
               const float* __restrict__ bias, const float* __restrict__ prj,
               const int* __restrict__ tok,
               float* __restrict__ cst, unsigned short* __restrict__ hout)
{
    __shared__ __align__(16) unsigned short Bs[8192];  // W: 8 tiles x 2 kc x 512 shorts = 16 KB

    const int tid  = threadIdx.x;
    const int lane = tid & 63;
    const int wave = tid >> 6;
    const int wm = wave >> 1, wn = wave & 1;
    const int m0 = blockIdx.y << 7;
    const int n0 = blockIdx.x << 7;

    const int r16  = lane & 15;
    const int koff = (lane >> 4) << 3;
    // A fragment base: row = m0 + wm*64 + i*16 + r16, k = t*64 + kc*32 + koff
    const size_t abase = (size_t)(m0 + (wm << 6) + r16) * HH + koff;
    // W staging (unchanged from r4)
    const unsigned wT0 = (unsigned)(n0 + (wave << 4) + r16) * HH + koff;
    const unsigned wT1 = wT0 + (unsigned)(64 * HH);

    floatx4 acc[4][4];
#pragma unroll
    for (int i = 0; i < 4; ++i)
#pragma unroll
        for (int j = 0; j < 4; ++j)
            acc[i][j] = (floatx4){0.f, 0.f, 0.f, 0.f};

    for (int t = 0; t < nchunk; ++t) {
        const unsigned short* Ap = (t & 16) ? A1 : A0;
        const unsigned short* Wp = (t & 16) ? W1 : W0;
        const unsigned kk = (unsigned)(t & 15) << 6;          // k = (t%16)*64
        // W -> LDS via DMA: 4 gl_lds per wave (16 KB total)
        gl_lds16(Wp + wT0 + kk,      Bs + (wave << 10));
        gl_lds16(Wp + wT0 + kk + 32, Bs + (wave << 10) + 512);
        gl_lds16(Wp + wT1 + kk,      Bs + ((wave + 4) << 10));
        gl_lds16(Wp + wT1 + kk + 32, Bs + ((wave + 4) << 10) + 512);
        // A -> VGPRs direct: 8 x 16B per lane (MFMA-ready fragments)
        short8 af[4][2];
#pragma unroll
        for (int i = 0; i < 4; ++i)
#pragma unroll
            for (int kc = 0; kc < 2; ++kc)
                af[i][kc] = *reinterpret_cast<const short8*>(
                    Ap + abase + (size_t)(i << 4) * HH + kk + (kc << 5));
        __syncthreads();               // drains vmcnt(0): W staged + A frags in regs

#pragma unroll
        for (int kc = 0; kc < 2; ++kc) {
            short8 bfr[4];
#pragma unroll
            for (int j = 0; j < 4; ++j)
                bfr[j] = *reinterpret_cast<const short8*>(Bs + ((((wn << 2) + j) << 10) + (kc << 9) + (lane << 3)));
#pragma unroll
            for (int i = 0; i < 4; ++i)
#pragma unroll
                for (int j = 0; j < 4; ++j)
                    acc[i][j] = __builtin_amdgcn_mfma_f32_16x16x32_bf16(af[i][kc], bfr[j], acc[i][j], 0, 0, 0);
        }
        __syncthreads();               // readers done before next chunk overwrites Bs
    }

    // ---- in-register LSTM cell epilogue (r4-verified) ----
    // col C = n0 + wn*64 + j*16 + r16 -> gate j of unit ub (permuted W layout)
    const int q = lane >> 4;
    const int ub = (((n0 >> 6) + wn) << 4) + r16;
    float bj[4];
#pragma unroll
    for (int j = 0; j < 4; ++j)
        bj[j] = bias[n0 + (wn << 6) + (j << 4) + r16];

#pragma unroll
    for (int i = 0; i < 4; ++i) {
#pragma unroll
        for (int p = 0; p < 4; ++p) {
            const int row = m0 + (wm << 6) + (i << 4) + (q << 2) + p;
            float g0 = acc[i][0][p] + bj[0];
            float g1 = acc[i][1][p] + bj[1];
            float g2 = acc[i][2][p] + bj[2];
            float g3 = acc[i][3][p] + bj[3];
            if (prj != nullptr) {
                const float* pr = prj + (size_t)tok[row] * G4H + n0 + (wn << 6) + r16;
                g0 += pr[0]; g1 += pr[16]; g2 += pr[32]; g3 += pr[48];
            }
            const float iv = sigm(g0);
            const float fv = sigm(g1);
            const float gv = tanh_(g2);
            const float ov = sigm(g3);
            const size_t ci = (size_t)row * HH + ub;
            const float cc = fv * cst[ci] + iv * gv;
            cst[ci] = cc;
            hout[ci] = f2bf(ov * tanh_(cc));
        }
    }
}

// ---------------- FC head, one timestep ----------------
__global__ __launch_bounds__(256)
void fc_step_kernel(const unsigned short* __restrict__ h1, const unsigned short* __restrict__ fcW,
                    const float* __restrict__ fcb,
                    float* __restrict__ out, int t) {
    int b    = (blockIdx.x * 256 + threadIdx.x) >> 6;
    int lane = threadIdx.x & 63;
    if (lane >= VV) return;
    const unsigned short* hrow = h1 + (size_t)b * HH;
    const unsigned short* wrow = fcW + (size_t)lane * HH;
    float acc = fcb[lane];
#pragma unroll 4
    for (int k8 = 0; k8 < HH / 8; ++k8) {
        short8 hv = *reinterpret_cast<const short8*>(hrow + k8 * 8);
        short8 wv = *reinterpret_cast<const short8*>(wrow + k8 * 8);
#pragma unroll
        for (int uu = 0; uu < 8; ++uu)
            acc += bf2f((unsigned short)hv[uu]) * bf2f((unsigned short)wv[uu]);
    }
    out[(size_t)b * OSTR + t * VV + lane] = acc;
}

extern "C" void kernel_launch(void* const* d_in, const int* in_sizes, int n_in,
                              void* d_out, int out_size, void* d_ws, size_t ws_size,
                              hipStream_t stream) {
    const int*   src    = (const int*)d_in[0];
    const int*   tgt    = (const int*)d_in[1];
    const float* emb    = (const float*)d_in[2];
    const float* eW_ih0 = (const float*)d_in[3];
    const float* eW_hh0 = (const float*)d_in[4];
    const float* eb_ih0 = (const float*)d_in[5];
    const float* eb_hh0 = (const float*)d_in[6];
    const float* eW_ih1 = (const float*)d_in[7];
    const float* eW_hh1 = (const float*)d_in[8];
    const float* eb_ih1 = (const float*)d_in[9];
    const float* eb_hh1 = (const float*)d_in[10];
    const float* dW_ih0 = (const float*)d_in[11];
    const float* dW_hh0 = (const float*)d_in[12];
    const float* db_ih0 = (const float*)d_in[13];
    const float* db_hh0 = (const float*)d_in[14];
    const float* dW_ih1 = (const float*)d_in[15];
    const float* dW_hh1 = (const float*)d_in[16];
    const float* db_ih1 = (const float*)d_in[17];
    const float* db_hh1 = (const float*)d_in[18];
    const float* fcW    = (const float*)d_in[19];
    const float* fcb    = (const float*)d_in[20];
    float* out = (float*)d_out;

    // ---- workspace layout ----
    char* w = (char*)d_ws;
    size_t off = 0;
    auto walloc = [&](size_t bytes) { void* p = w + off; off += (bytes + 255) & ~(size_t)255; return p; };
    unsigned short* bW[8];
    const float* srcW[8] = {eW_ih0, eW_hh0, eW_ih1, eW_hh1, dW_ih0, dW_hh0, dW_ih1, dW_hh1};
    const int     szW[8] = {G4H*EE, G4H*HH, G4H*HH, G4H*HH, G4H*EE, G4H*HH, G4H*HH, G4H*HH};
    for (int i = 0; i < 8; ++i) bW[i] = (unsigned short*)walloc((size_t)szW[i] * 2);
    unsigned short* bfcW = (unsigned short*)walloc((size_t)VV * HH * 2);
    // zero region: h0a, h1a (bf16) + c0, c1 (fp32) — contiguous 24 MiB
    unsigned short* h0a = (unsigned short*)walloc((size_t)BB * HH * 2);
    unsigned short* h1a = (unsigned short*)walloc((size_t)BB * HH * 2);
    float* c0 = (float*)walloc((size_t)BB * HH * 4);
    float* c1 = (float*)walloc((size_t)BB * HH * 4);
    unsigned short* h0b = (unsigned short*)walloc((size_t)BB * HH * 2);
    unsigned short* h1b = (unsigned short*)walloc((size_t)BB * HH * 2);
    float* bsum = (float*)walloc((size_t)4 * G4H * 4);
    int*   toks = (int*)walloc((size_t)2 * SS * BB * 4);
    float* proj = (float*)walloc((size_t)2 * VV * G4H * 4);

    unsigned short* h0[2] = {h0a, h0b};
    unsigned short* h1[2] = {h1a, h1b};

    // ---- setup: permuted weights (K=1024 only; W_ih0 via proj), biases, tokens ----
    for (int i = 0; i < 8; ++i) {
        if (i == 0 || i == 4) continue;               // eW_ih0/dW_ih0: replaced by proj tables
        cvt_perm_kernel<<<(szW[i] / 4) / 256, 256, 0, stream>>>(srcW[i], bW[i]);
    }
    cvt_f2b_kernel<<<(VV * HH / 4 + 255) / 256, 256, 0, stream>>>(fcW, bfcW, VV * HH / 4);
    zero16_kernel<<<6144, 256, 0, stream>>>((uint4*)h0a);
    bias_sum_kernel<<<64, 256, 0, stream>>>(eb_ih0, eb_hh0, eb_ih1, eb_hh1,
                                            db_ih0, db_hh0, db_ih1, db_hh1, bsum);
    tok_kernel<<<384, 256, 0, stream>>>(src, tgt, toks);
    proj_kernel<<<2 * VV * 16, 256, 0, stream>>>(emb, eW_ih0, dW_ih0, proj);

    dim3 ggrid(G4H / 128, BB / 128);   // (32, 16) = 512 blocks = 2/CU

    int p = 0;
    for (int t = 0; t < 2 * SS; ++t) {
        const int enc = (t < SS);
        const unsigned short* Whh0 = enc ? bW[1] : bW[5];
        const unsigned short* Whh1 = enc ? bW[3] : bW[7];
        const unsigned short* Wih1 = enc ? bW[2] : bW[6];
        const float* b0 = bsum + (size_t)(enc ? 0 : 2) * G4H;
        const float* b1 = bsum + (size_t)(enc ? 1 : 3) * G4H;
        const float* pj = proj + (size_t)(enc ? 0 : 1) * VV * G4H;

        // L0: h0' = cell(h0 @ Whh0^T + proj[tok] + b0)   — 16 chunks (K=1024)
        lstm_step<<<ggrid, 256, 0, stream>>>(
            h0[p], Whh0, h0[p], Whh0, 16, b0, pj, toks + (size_t)t * BB, c0, h0[p ^ 1]);
        // L1: h1' = cell(h1 @ Whh1^T + h0' @ Wih1^T + b1) — 32 chunks (K=2048)
        lstm_step<<<ggrid, 256, 0, stream>>>(
            h1[p], Whh1, h0[p ^ 1], Wih1, 32, b1, nullptr, nullptr, c1, h1[p ^ 1]);
        if (!enc)
            fc_step_kernel<<<512, 256, 0, stream>>>(h1[p ^ 1], bfcW, fcb, out, t - SS);
        p ^= 1;
    }
}

// Round 10
// 5052.508 us; speedup vs baseline: 1.6766x; 1.6766x over previous
//
#include <hip/hip_runtime.h>

typedef __attribute__((ext_vector_type(8))) short short8;
typedef __attribute__((ext_vector_type(4))) float floatx4;

#define BB 2048   // batch
#define SS 24     // seq len (src and tgt)
#define HH 1024   // hidden
#define VV 37     // vocab
#define EE 256    // embed
#define G4H 4096  // 4*H gates
#define OSTR (SS * VV)   // out row stride = 888

__device__ __forceinline__ unsigned short f2bf(float f) {
    union { float f; unsigned u; } x; x.f = f;
    unsigned r = x.u + 0x7FFF + ((x.u >> 16) & 1);   // RNE
    return (unsigned short)(r >> 16);
}
__device__ __forceinline__ float bf2f(unsigned short s) {
    union { unsigned u; float f; } x; x.u = ((unsigned)s) << 16; return x.f;
}
__device__ __forceinline__ float sigm(float x) {
    x = fminf(fmaxf(x, -15.f), 15.f);
    return 1.f / (1.f + __expf(-x));
}
__device__ __forceinline__ float tanh_(float x) {
    x = fminf(fmaxf(x, -15.f), 15.f);
    float e = __expf(2.f * x);
    return (e - 1.f) / (e + 1.f);
}

// permuted W row C <- original row: gate g=(C>>4)&3 (i,f,g,o), unit u=(C>>6)*16+(C&15)
__device__ __forceinline__ int wrow_orig(int C) {
    return (((C >> 4) & 3) << 10) | ((C >> 6) << 4) | (C & 15);
}

// async global->LDS DMA, 16B/lane; LDS dest = wave-uniform base + lane*16 [m97/m104]
typedef const __attribute__((address_space(1))) void* gas_t;
typedef __attribute__((address_space(3))) void* las_t;
__device__ __forceinline__ void gl_lds16(const void* g, void* l) {
    __builtin_amdgcn_global_load_lds((gas_t)g, (las_t)l, 16, 0, 0);
}

// ---------------- fp32 -> bf16 plain conversion (fcW) ----------------
__global__ __launch_bounds__(256)
void cvt_f2b_kernel(const float* __restrict__ s, unsigned short* __restrict__ d, int n4) {
    int i = blockIdx.x * 256 + threadIdx.x;
    if (i >= n4) return;
    float4 v = reinterpret_cast<const float4*>(s)[i];
    ushort4 o;
    o.x = f2bf(v.x); o.y = f2bf(v.y); o.z = f2bf(v.z); o.w = f2bf(v.w);
    reinterpret_cast<ushort4*>(d)[i] = o;
}

// ------- fp32 -> bf16 packed-fragment layout for K=1024 weights -------
// Granule blk = ct*32 + kb (ct: 16-col tile, kb: 32-elem k-granule), 512 shorts each.
// packed[blk*512 + l*8 + e] = W[orig(ct*16 + (l&15))][kb*32 + (l>>4)*8 + e]
// => one wave-wide gl_lds of a granule reads 1 KB CONTIGUOUS (16 cache lines in-order),
//    and lands in LDS in exactly the MFMA B-fragment layout (col=l&15, k=(l>>4)*8+e).
__global__ __launch_bounds__(256)
void cvt_pack_kernel(const float* __restrict__ s, unsigned short* __restrict__ d) {
    int g = blockIdx.x * 256 + threadIdx.x;      // 4096*1024/8 = 524288 granule-slots
    int l   = g & 63;
    int blk = g >> 6;
    int kb  = blk & 31;
    int ct  = blk >> 5;
    int col = (ct << 4) + (l & 15);
    int k0  = (kb << 5) + ((l >> 4) << 3);
    const float* sp = s + (size_t)wrow_orig(col) * 1024 + k0;
    float4 v0 = *reinterpret_cast<const float4*>(sp);
    float4 v1 = *reinterpret_cast<const float4*>(sp + 4);
    ushort4 o0, o1;
    o0.x = f2bf(v0.x); o0.y = f2bf(v0.y); o0.z = f2bf(v0.z); o0.w = f2bf(v0.w);
    o1.x = f2bf(v1.x); o1.y = f2bf(v1.y); o1.z = f2bf(v1.z); o1.w = f2bf(v1.w);
    reinterpret_cast<ushort4*>(d)[(size_t)g * 2]     = o0;
    reinterpret_cast<ushort4*>(d)[(size_t)g * 2 + 1] = o1;
}

// ---------------- zero init (h0a,h1a bf16 + c0,c1 fp32 region, 24 MiB) ----------------
__global__ __launch_bounds__(256) void zero16_kernel(uint4* __restrict__ p) {
    uint4 z; z.x = 0; z.y = 0; z.z = 0; z.w = 0;
    p[(size_t)blockIdx.x * 256 + threadIdx.x] = z;
}

// ---------------- token matrix [2,S,B] ----------------
__global__ __launch_bounds__(256)
void tok_kernel(const int* __restrict__ src, const int* __restrict__ tgt, int* __restrict__ toks) {
    int idx = blockIdx.x * 256 + threadIdx.x;   // 2*24*2048
    int b  = idx & 2047;
    int st = idx >> 11;
    int tok;
    if (st < SS) tok = src[b * SS + st];
    else { int t = st - SS; tok = (t == 0) ? 1 : tgt[b * SS + (t - 1)]; }
    toks[idx] = tok;
}

// ---------------- per-layer bias sums, permuted layout ----------------
__global__ __launch_bounds__(256) void bias_sum_kernel(
        const float* e0i, const float* e0h, const float* e1i, const float* e1h,
        const float* d0i, const float* d0h, const float* d1i, const float* d1h,
        float* __restrict__ out) {
    int idx = blockIdx.x * 256 + threadIdx.x;   // 4*4096
    int layer = idx >> 12, C = idx & 4095;
    int src_j = wrow_orig(C);
    const float* pi; const float* ph;
    switch (layer) {
        case 0:  pi = e0i; ph = e0h; break;
        case 1:  pi = e1i; ph = e1h; break;
        case 2:  pi = d0i; ph = d0h; break;
        default: pi = d1i; ph = d1h; break;
    }
    out[idx] = pi[src_j] + ph[src_j];
}

// ---------------- fp32 input-projection tables: proj[table][v][C] ----------------
__global__ __launch_bounds__(256)
void proj_kernel(const float* __restrict__ emb, const float* __restrict__ eWih,
                 const float* __restrict__ dWih, float* __restrict__ proj) {
    // grid = 2 tables * 37 v * 16 C-blocks = 1184
    int bid = blockIdx.x;
    int table = bid / (VV * 16);
    int rem   = bid - table * (VV * 16);
    int v     = rem >> 4;
    int cblk  = rem & 15;
    const float* W = table ? dWih : eWih;
    __shared__ float es[EE];
    es[threadIdx.x] = emb[v * EE + threadIdx.x];
    __syncthreads();
    int C = (cblk << 8) + threadIdx.x;
    const float* wr = W + (size_t)wrow_orig(C) * EE;
    float acc = 0.f;
#pragma unroll 8
    for (int k = 0; k < EE; ++k) acc += es[k] * wr[k];
    proj[((size_t)table * VV + v) * G4H + C] = acc;
}

// ---------------- LSTM step GEMM + cell (r4 loop, BK=128, packed-W staging) --------
// gates[2048,4096] = A0 @ W0p^T (+ A1 @ W1p^T for 2nd half) + bias (+ proj[tok])
// 128x128 tile, BK=128 (16 gl_lds/wave, 64 MFMA/wave per drain), 64 KB LDS,
// W granules contiguous-1KB per gl_lds; A staged as r4. In-register LSTM epilogue.
__global__ __launch_bounds__(256, 2)
void lstm_step(const unsigned short* __restrict__ A0, const unsigned short* __restrict__ W0,
               const unsigned short* __restrict__ A1, const unsigned short* __restrict__ W1,
               int nchunk,
               const float* __restrict__ bias, const float* __restrict__ prj,
               const int* __restrict__ tok,
               float* __restrict__ cst, unsigned short* __restrict__ hout)
{
    __shared__ __align__(16) unsigned short As[16384];  // 8 tiles x 4 kc x 512 = 32 KB
    __shared__ __align__(16) unsigned short Bs[16384];  // 32 KB

    const int tid  = threadIdx.x;
    const int lane = tid & 63;
    const int wave = tid >> 6;
    const int wm = wave >> 1, wn = wave & 1;
    const int m0 = blockIdx.y << 7;
    const int n0 = blockIdx.x << 7;

    const int r16  = lane & 15;
    const int koff = (lane >> 4) << 3;
    const unsigned aT0 = (unsigned)(m0 + (wave << 4) + r16) * HH + koff;
    const unsigned aT1 = aT0 + (unsigned)(64 * HH);
    const int ctb = n0 >> 4;                 // first of 8 16-col tiles
    const size_t wlane = (size_t)(lane << 3);

    floatx4 acc[4][4];
#pragma unroll
    for (int i = 0; i < 4; ++i)
#pragma unroll
        for (int j = 0; j < 4; ++j)
            acc[i][j] = (floatx4){0.f, 0.f, 0.f, 0.f};

    for (int t = 0; t < nchunk; ++t) {
        const unsigned short* Ap = (t & 8) ? A1 : A0;
        const unsigned short* Wp = (t & 8) ? W1 : W0;
        const unsigned kk  = (unsigned)(t & 7) << 7;   // element k base
        const int      kb0 = (t & 7) << 2;             // granule base
#pragma unroll
        for (int kc = 0; kc < 4; ++kc) {
            gl_lds16(Ap + aT0 + kk + (kc << 5), As + (wave << 11) + (kc << 9));
            gl_lds16(Ap + aT1 + kk + (kc << 5), As + ((wave + 4) << 11) + (kc << 9));
            gl_lds16(Wp + (((size_t)((ctb + wave) << 5) + kb0 + kc) << 9) + wlane,
                     Bs + (wave << 11) + (kc << 9));
            gl_lds16(Wp + (((size_t)((ctb + wave + 4) << 5) + kb0 + kc) << 9) + wlane,
                     Bs + ((wave + 4) << 11) + (kc << 9));
        }
        __syncthreads();               // drains vmcnt(0): staged data visible to all waves

#pragma unroll
        for (int kc = 0; kc < 4; ++kc) {
            short8 af[4], bfr[4];
#pragma unroll
            for (int i = 0; i < 4; ++i) {
                af[i]  = *reinterpret_cast<const short8*>(As + ((((wm << 2) + i) << 11) + (kc << 9) + (lane << 3)));
                bfr[i] = *reinterpret_cast<const short8*>(Bs + ((((wn << 2) + i) << 11) + (kc << 9) + (lane << 3)));
            }
#pragma unroll
            for (int i = 0; i < 4; ++i)
#pragma unroll
                for (int j = 0; j < 4; ++j)
                    acc[i][j] = __builtin_amdgcn_mfma_f32_16x16x32_bf16(af[i], bfr[j], acc[i][j], 0, 0, 0);
        }
        __syncthreads();               // readers done before next chunk overwrites
    }

    // ---- in-register LSTM cell epilogue (r4-verified) ----
    // col C = n0 + wn*64 + j*16 + r16 -> gate j of unit ub (permuted W layout)
    const int q = lane >> 4;
    const int ub = (((n0 >> 6) + wn) << 4) + r16;
    float bj[4];
#pragma unroll
    for (int j = 0; j < 4; ++j)
        bj[j] = bias[n0 + (wn << 6) + (j << 4) + r16];

#pragma unroll
    for (int i = 0; i < 4; ++i) {
#pragma unroll
        for (int p = 0; p < 4; ++p) {
            const int row = m0 + (wm << 6) + (i << 4) + (q << 2) + p;
            float g0 = acc[i][0][p] + bj[0];
            float g1 = acc[i][1][p] + bj[1];
            float g2 = acc[i][2][p] + bj[2];
            float g3 = acc[i][3][p] + bj[3];
            if (prj != nullptr) {
                const float* pr = prj + (size_t)tok[row] * G4H + n0 + (wn << 6) + r16;
                g0 += pr[0]; g1 += pr[16]; g2 += pr[32]; g3 += pr[48];
            }
            const float iv = sigm(g0);
            const float fv = sigm(g1);
            const float gv = tanh_(g2);
            const float ov = sigm(g3);
            const size_t ci = (size_t)row * HH + ub;
            const float cc = fv * cst[ci] + iv * gv;
            cst[ci] = cc;
            hout[ci] = f2bf(ov * tanh_(cc));
        }
    }
}

// ---------------- FC head, one timestep ----------------
__global__ __launch_bounds__(256)
void fc_step_kernel(const unsigned short* __restrict__ h1, const unsigned short* __restrict__ fcW,
                    const float* __restrict__ fcb,
                    float* __restrict__ out, int t) {
    int b    = (blockIdx.x * 256 + threadIdx.x) >> 6;
    int lane = threadIdx.x & 63;
    if (lane >= VV) return;
    const unsigned short* hrow = h1 + (size_t)b * HH;
    const unsigned short* wrow = fcW + (size_t)lane * HH;
    float acc = fcb[lane];
#pragma unroll 4
    for (int k8 = 0; k8 < HH / 8; ++k8) {
        short8 hv = *reinterpret_cast<const short8*>(hrow + k8 * 8);
        short8 wv = *reinterpret_cast<const short8*>(wrow + k8 * 8);
#pragma unroll
        for (int uu = 0; uu < 8; ++uu)
            acc += bf2f((unsigned short)hv[uu]) * bf2f((unsigned short)wv[uu]);
    }
    out[(size_t)b * OSTR + t * VV + lane] = acc;
}

extern "C" void kernel_launch(void* const* d_in, const int* in_sizes, int n_in,
                              void* d_out, int out_size, void* d_ws, size_t ws_size,
                              hipStream_t stream) {
    const int*   src    = (const int*)d_in[0];
    const int*   tgt    = (const int*)d_in[1];
    const float* emb    = (const float*)d_in[2];
    const float* eW_ih0 = (const float*)d_in[3];
    const float* eW_hh0 = (const float*)d_in[4];
    const float* eb_ih0 = (const float*)d_in[5];
    const float* eb_hh0 = (const float*)d_in[6];
    const float* eW_ih1 = (const float*)d_in[7];
    const float* eW_hh1 = (const float*)d_in[8];
    const float* eb_ih1 = (const float*)d_in[9];
    const float* eb_hh1 = (const float*)d_in[10];
    const float* dW_ih0 = (const float*)d_in[11];
    const float* dW_hh0 = (const float*)d_in[12];
    const float* db_ih0 = (const float*)d_in[13];
    const float* db_hh0 = (const float*)d_in[14];
    const float* dW_ih1 = (const float*)d_in[15];
    const float* dW_hh1 = (const float*)d_in[16];
    const float* db_ih1 = (const float*)d_in[17];
    const float* db_hh1 = (const float*)d_in[18];
    const float* fcW    = (const float*)d_in[19];
    const float* fcb    = (const float*)d_in[20];
    float* out = (float*)d_out;

    // ---- workspace layout ----
    char* w = (char*)d_ws;
    size_t off = 0;
    auto walloc = [&](size_t bytes) { void* p = w + off; off += (bytes + 255) & ~(size_t)255; return p; };
    unsigned short* bW[8];
    const float* srcW[8] = {eW_ih0, eW_hh0, eW_ih1, eW_hh1, dW_ih0, dW_hh0, dW_ih1, dW_hh1};
    const int     szW[8] = {G4H*EE, G4H*HH, G4H*HH, G4H*HH, G4H*EE, G4H*HH, G4H*HH, G4H*HH};
    for (int i = 0; i < 8; ++i) bW[i] = (unsigned short*)walloc((size_t)szW[i] * 2);
    unsigned short* bfcW = (unsigned short*)walloc((size_t)VV * HH * 2);
    // zero region: h0a, h1a (bf16) + c0, c1 (fp32) — contiguous 24 MiB
    unsigned short* h0a = (unsigned short*)walloc((size_t)BB * HH * 2);
    unsigned short* h1a = (unsigned short*)walloc((size_t)BB * HH * 2);
    float* c0 = (float*)walloc((size_t)BB * HH * 4);
    float* c1 = (float*)walloc((size_t)BB * HH * 4);
    unsigned short* h0b = (unsigned short*)walloc((size_t)BB * HH * 2);
    unsigned short* h1b = (unsigned short*)walloc((size_t)BB * HH * 2);
    float* bsum = (float*)walloc((size_t)4 * G4H * 4);
    int*   toks = (int*)walloc((size_t)2 * SS * BB * 4);
    float* proj = (float*)walloc((size_t)2 * VV * G4H * 4);

    unsigned short* h0[2] = {h0a, h0b};
    unsigned short* h1[2] = {h1a, h1b};

    // ---- setup: packed weights (K=1024 only; W_ih0 via proj), biases, tokens ----
    for (int i = 0; i < 8; ++i) {
        if (i == 0 || i == 4) continue;               // eW_ih0/dW_ih0: replaced by proj tables
        cvt_pack_kernel<<<2048, 256, 0, stream>>>(srcW[i], bW[i]);
    }
    cvt_f2b_kernel<<<(VV * HH / 4 + 255) / 256, 256, 0, stream>>>(fcW, bfcW, VV * HH / 4);
    zero16_kernel<<<6144, 256, 0, stream>>>((uint4*)h0a);
    bias_sum_kernel<<<64, 256, 0, stream>>>(eb_ih0, eb_hh0, eb_ih1, eb_hh1,
                                            db_ih0, db_hh0, db_ih1, db_hh1, bsum);
    tok_kernel<<<384, 256, 0, stream>>>(src, tgt, toks);
    proj_kernel<<<2 * VV * 16, 256, 0, stream>>>(emb, eW_ih0, dW_ih0, proj);

    dim3 ggrid(G4H / 128, BB / 128);   // (32, 16) = 512 blocks = 2/CU

    int p = 0;
    for (int t = 0; t < 2 * SS; ++t) {
        const int enc = (t < SS);
        const unsigned short* Whh0 = enc ? bW[1] : bW[5];
        const unsigned short* Whh1 = enc ? bW[3] : bW[7];
        const unsigned short* Wih1 = enc ? bW[2] : bW[6];
        const float* b0 = bsum + (size_t)(enc ? 0 : 2) * G4H;
        const float* b1 = bsum + (size_t)(enc ? 1 : 3) * G4H;
        const float* pj = proj + (size_t)(enc ? 0 : 1) * VV * G4H;

        // L0: h0' = cell(h0 @ Whh0^T + proj[tok] + b0)   — 8 chunks (K=1024)
        lstm_step<<<ggrid, 256, 0, stream>>>(
            h0[p], Whh0, h0[p], Whh0, 8, b0, pj, toks + (size_t)t * BB, c0, h0[p ^ 1]);
        // L1: h1' = cell(h1 @ Whh1^T + h0' @ Wih1^T + b1) — 16 chunks (K=2048)
        lstm_step<<<ggrid, 256, 0, stream>>>(
            h1[p], Whh1, h0[p ^ 1], Wih1, 16, b1, nullptr, nullptr, c1, h1[p ^ 1]);
        if (!enc)
            fc_step_kernel<<<512, 256, 0, stream>>>(h1[p ^ 1], bfcW, fcb, out, t - SS);
        p ^= 1;
    }
}

// Round 11
// 4592.737 us; speedup vs baseline: 1.8444x; 1.1001x over previous
//
#include <hip/hip_runtime.h>

typedef __attribute__((ext_vector_type(8))) short short8;
typedef __attribute__((ext_vector_type(4))) float floatx4;

#define BB 2048   // batch
#define SS 24     // seq len (src and tgt)
#define HH 1024   // hidden
#define VV 37     // vocab
#define EE 256    // embed
#define G4H 4096  // 4*H gates
#define OSTR (SS * VV)   // out row stride = 888

__device__ __forceinline__ unsigned short f2bf(float f) {
    union { float f; unsigned u; } x; x.f = f;
    unsigned r = x.u + 0x7FFF + ((x.u >> 16) & 1);   // RNE
    return (unsigned short)(r >> 16);
}
__device__ __forceinline__ float bf2f(unsigned short s) {
    union { unsigned u; float f; } x; x.u = ((unsigned)s) << 16; return x.f;
}
__device__ __forceinline__ float sigm(float x) {
    x = fminf(fmaxf(x, -15.f), 15.f);
    return 1.f / (1.f + __expf(-x));
}
__device__ __forceinline__ float tanh_(float x) {
    x = fminf(fmaxf(x, -15.f), 15.f);
    float e = __expf(2.f * x);
    return (e - 1.f) / (e + 1.f);
}

// permuted W row C <- original row: gate g=(C>>4)&3 (i,f,g,o), unit u=(C>>6)*16+(C&15)
__device__ __forceinline__ int wrow_orig(int C) {
    return (((C >> 4) & 3) << 10) | ((C >> 6) << 4) | (C & 15);
}

// async global->LDS DMA, 16B/lane; LDS dest = wave-uniform base + lane*16 [m97/m104]
typedef const __attribute__((address_space(1))) void* gas_t;
typedef __attribute__((address_space(3))) void* las_t;
__device__ __forceinline__ void gl_lds16(const void* g, void* l) {
    __builtin_amdgcn_global_load_lds((gas_t)g, (las_t)l, 16, 0, 0);
}

// ---------------- fp32 -> bf16 plain conversion (fcW) ----------------
__global__ __launch_bounds__(256)
void cvt_f2b_kernel(const float* __restrict__ s, unsigned short* __restrict__ d, int n4) {
    int i = blockIdx.x * 256 + threadIdx.x;
    if (i >= n4) return;
    float4 v = reinterpret_cast<const float4*>(s)[i];
    ushort4 o;
    o.x = f2bf(v.x); o.y = f2bf(v.y); o.z = f2bf(v.z); o.w = f2bf(v.w);
    reinterpret_cast<ushort4*>(d)[i] = o;
}

// ------- fp32 -> bf16 packed-fragment layout for K=1024 weights -------
// Granule blk = ct*32 + kb (ct: 16-col tile, kb: 32-elem k-granule), 512 shorts each.
// packed[blk*512 + l*8 + e] = W[orig(ct*16 + (l&15))][kb*32 + (l>>4)*8 + e]
// => one wave-wide gl_lds of a granule reads 1 KB CONTIGUOUS, landing in LDS in
//    exactly the MFMA B-fragment layout.
__global__ __launch_bounds__(256)
void cvt_pack_kernel(const float* __restrict__ s, unsigned short* __restrict__ d) {
    int g = blockIdx.x * 256 + threadIdx.x;      // 4096*1024/8 = 524288 granule-slots
    int l   = g & 63;
    int blk = g >> 6;
    int kb  = blk & 31;
    int ct  = blk >> 5;
    int col = (ct << 4) + (l & 15);
    int k0  = (kb << 5) + ((l >> 4) << 3);
    const float* sp = s + (size_t)wrow_orig(col) * 1024 + k0;
    float4 v0 = *reinterpret_cast<const float4*>(sp);
    float4 v1 = *reinterpret_cast<const float4*>(sp + 4);
    ushort4 o0, o1;
    o0.x = f2bf(v0.x); o0.y = f2bf(v0.y); o0.z = f2bf(v0.z); o0.w = f2bf(v0.w);
    o1.x = f2bf(v1.x); o1.y = f2bf(v1.y); o1.z = f2bf(v1.z); o1.w = f2bf(v1.w);
    reinterpret_cast<ushort4*>(d)[(size_t)g * 2]     = o0;
    reinterpret_cast<ushort4*>(d)[(size_t)g * 2 + 1] = o1;
}

// ---------------- zero init (h0a,h1a bf16 + c0,c1 fp32 region, 24 MiB) ----------------
__global__ __launch_bounds__(256) void zero16_kernel(uint4* __restrict__ p) {
    uint4 z; z.x = 0; z.y = 0; z.z = 0; z.w = 0;
    p[(size_t)blockIdx.x * 256 + threadIdx.x] = z;
}

// ---------------- token matrix [2,S,B] ----------------
__global__ __launch_bounds__(256)
void tok_kernel(const int* __restrict__ src, const int* __restrict__ tgt, int* __restrict__ toks) {
    int idx = blockIdx.x * 256 + threadIdx.x;   // 2*24*2048
    int b  = idx & 2047;
    int st = idx >> 11;
    int tok;
    if (st < SS) tok = src[b * SS + st];
    else { int t = st - SS; tok = (t == 0) ? 1 : tgt[b * SS + (t - 1)]; }
    toks[idx] = tok;
}

// ---------------- per-layer bias sums, permuted layout ----------------
__global__ __launch_bounds__(256) void bias_sum_kernel(
        const float* e0i, const float* e0h, const float* e1i, const float* e1h,
        const float* d0i, const float* d0h, const float* d1i, const float* d1h,
        float* __restrict__ out) {
    int idx = blockIdx.x * 256 + threadIdx.x;   // 4*4096
    int layer = idx >> 12, C = idx & 4095;
    int src_j = wrow_orig(C);
    const float* pi; const float* ph;
    switch (layer) {
        case 0:  pi = e0i; ph = e0h; break;
        case 1:  pi = e1i; ph = e1h; break;
        case 2:  pi = d0i; ph = d0h; break;
        default: pi = d1i; ph = d1h; break;
    }
    out[idx] = pi[src_j] + ph[src_j];
}

// ---------------- fp32 input-projection tables: proj[table][v][C] ----------------
__global__ __launch_bounds__(256)
void proj_kernel(const float* __restrict__ emb, const float* __restrict__ eWih,
                 const float* __restrict__ dWih, float* __restrict__ proj) {
    // grid = 2 tables * 37 v * 16 C-blocks = 1184
    int bid = blockIdx.x;
    int table = bid / (VV * 16);
    int rem   = bid - table * (VV * 16);
    int v     = rem >> 4;
    int cblk  = rem & 15;
    const float* W = table ? dWih : eWih;
    __shared__ float es[EE];
    es[threadIdx.x] = emb[v * EE + threadIdx.x];
    __syncthreads();
    int C = (cblk << 8) + threadIdx.x;
    const float* wr = W + (size_t)wrow_orig(C) * EE;
    float acc = 0.f;
#pragma unroll 8
    for (int k = 0; k < EE; ++k) acc += es[k] * wr[k];
    proj[((size_t)table * VV + v) * G4H + C] = acc;
}

// ---------------- LSTM step GEMM + cell (BK=128, BOTH operands packed-granule) ----
// gates[2048,4096] = A0 @ W0p^T (+ A1 @ W1p^T for 2nd half) + bias (+ proj[tok])
// h matrices stored in A-fragment-granule layout: granule (rt,kb) = 1 KB contiguous,
// packed[(rt*32+kb)*512 + l*8 + e] = h[rt*16+(l&15)][kb*32+(l>>4)*8+e].
// => every gl_lds in the K-loop reads 1 KB contiguous. 64 KB LDS, 2 blocks/CU.
// In-register LSTM epilogue writes h back in packed layout.
__global__ __launch_bounds__(256, 2)
void lstm_step(const unsigned short* __restrict__ A0, const unsigned short* __restrict__ W0,
               const unsigned short* __restrict__ A1, const unsigned short* __restrict__ W1,
               int nchunk,
               const float* __restrict__ bias, const float* __restrict__ prj,
               const int* __restrict__ tok,
               float* __restrict__ cst, unsigned short* __restrict__ hout)
{
    __shared__ __align__(16) unsigned short As[16384];  // 8 tiles x 4 kc x 512 = 32 KB
    __shared__ __align__(16) unsigned short Bs[16384];  // 32 KB

    const int tid  = threadIdx.x;
    const int lane = tid & 63;
    const int wave = tid >> 6;
    const int wm = wave >> 1, wn = wave & 1;
    const int m0 = blockIdx.y << 7;
    const int n0 = blockIdx.x << 7;

    const int r16 = lane & 15;
    const int rtb = m0 >> 4;                 // first of 8 16-row A tiles
    const int ctb = n0 >> 4;                 // first of 8 16-col W tiles
    const size_t wlane = (size_t)(lane << 3);

    floatx4 acc[4][4];
#pragma unroll
    for (int i = 0; i < 4; ++i)
#pragma unroll
        for (int j = 0; j < 4; ++j)
            acc[i][j] = (floatx4){0.f, 0.f, 0.f, 0.f};

    for (int t = 0; t < nchunk; ++t) {
        const unsigned short* Ap = (t & 8) ? A1 : A0;
        const unsigned short* Wp = (t & 8) ? W1 : W0;
        const int kb0 = (t & 7) << 2;             // granule base within segment
#pragma unroll
        for (int kc = 0; kc < 4; ++kc) {
            gl_lds16(Ap + (((size_t)((rtb + wave) << 5) + kb0 + kc) << 9) + wlane,
                     As + (wave << 11) + (kc << 9));
            gl_lds16(Ap + (((size_t)((rtb + wave + 4) << 5) + kb0 + kc) << 9) + wlane,
                     As + ((wave + 4) << 11) + (kc << 9));
            gl_lds16(Wp + (((size_t)((ctb + wave) << 5) + kb0 + kc) << 9) + wlane,
                     Bs + (wave << 11) + (kc << 9));
            gl_lds16(Wp + (((size_t)((ctb + wave + 4) << 5) + kb0 + kc) << 9) + wlane,
                     Bs + ((wave + 4) << 11) + (kc << 9));
        }
        __syncthreads();               // drains vmcnt(0): staged data visible to all waves

#pragma unroll
        for (int kc = 0; kc < 4; ++kc) {
            short8 af[4], bfr[4];
#pragma unroll
            for (int i = 0; i < 4; ++i) {
                af[i]  = *reinterpret_cast<const short8*>(As + ((((wm << 2) + i) << 11) + (kc << 9) + (lane << 3)));
                bfr[i] = *reinterpret_cast<const short8*>(Bs + ((((wn << 2) + i) << 11) + (kc << 9) + (lane << 3)));
            }
#pragma unroll
            for (int i = 0; i < 4; ++i)
#pragma unroll
                for (int j = 0; j < 4; ++j)
                    acc[i][j] = __builtin_amdgcn_mfma_f32_16x16x32_bf16(af[i], bfr[j], acc[i][j], 0, 0, 0);
        }
        __syncthreads();               // readers done before next chunk overwrites
    }

    // ---- in-register LSTM cell epilogue ----
    // col C = n0 + wn*64 + j*16 + r16 -> gate j of unit ub (permuted W layout)
    const int q = lane >> 4;
    const int ub = (((n0 >> 6) + wn) << 4) + r16;
    float bj[4];
#pragma unroll
    for (int j = 0; j < 4; ++j)
        bj[j] = bias[n0 + (wn << 6) + (j << 4) + r16];

    // packed-h write constants for unit ub: granule-k = ub>>5, lane-part, elem
    const int kbu = ub >> 5;
    const int lq  = ((ub & 31) >> 3) << 4;
    const int eu  = ub & 7;

#pragma unroll
    for (int i = 0; i < 4; ++i) {
#pragma unroll
        for (int p = 0; p < 4; ++p) {
            const int row = m0 + (wm << 6) + (i << 4) + (q << 2) + p;
            float g0 = acc[i][0][p] + bj[0];
            float g1 = acc[i][1][p] + bj[1];
            float g2 = acc[i][2][p] + bj[2];
            float g3 = acc[i][3][p] + bj[3];
            if (prj != nullptr) {
                const float* pr = prj + (size_t)tok[row] * G4H + n0 + (wn << 6) + r16;
                g0 += pr[0]; g1 += pr[16]; g2 += pr[32]; g3 += pr[48];
            }
            const float iv = sigm(g0);
            const float fv = sigm(g1);
            const float gv = tanh_(g2);
            const float ov = sigm(g3);
            const size_t ci = (size_t)row * HH + ub;          // c stays row-major
            const float cc = fv * cst[ci] + iv * gv;
            cst[ci] = cc;
            // h in packed-granule layout: rt = row>>4, lane = lq + (row&15)
            const size_t hi = ((((size_t)((row >> 4) << 5) + kbu) << 6) + lq + (q << 2) + p) * 8 + eu;
            hout[hi] = f2bf(ov * tanh_(cc));
        }
    }
}

// ---------------- FC head, one timestep (h1 in packed-granule layout) ----------------
__global__ __launch_bounds__(256)
void fc_step_kernel(const unsigned short* __restrict__ h1, const unsigned short* __restrict__ fcW,
                    const float* __restrict__ fcb,
                    float* __restrict__ out, int t) {
    int b    = (blockIdx.x * 256 + threadIdx.x) >> 6;
    int lane = threadIdx.x & 63;
    if (lane >= VV) return;
    const unsigned short* wrow = fcW + (size_t)lane * HH;
    float acc = fcb[lane];
    const size_t rtb = (size_t)(b >> 4) << 5;   // granule base for this row
    const int    r   = b & 15;
#pragma unroll 4
    for (int k8 = 0; k8 < HH / 8; ++k8) {
        // units k8*8..k8*8+7 live contiguously at granule rtb+(k8>>2), lane (k8&3)*16+r
        short8 hv = *reinterpret_cast<const short8*>(
            h1 + (((rtb + (k8 >> 2)) << 6) + ((k8 & 3) << 4) + r) * 8);
        short8 wv = *reinterpret_cast<const short8*>(wrow + k8 * 8);
#pragma unroll
        for (int uu = 0; uu < 8; ++uu)
            acc += bf2f((unsigned short)hv[uu]) * bf2f((unsigned short)wv[uu]);
    }
    out[(size_t)b * OSTR + t * VV + lane] = acc;
}

extern "C" void kernel_launch(void* const* d_in, const int* in_sizes, int n_in,
                              void* d_out, int out_size, void* d_ws, size_t ws_size,
                              hipStream_t stream) {
    const int*   src    = (const int*)d_in[0];
    const int*   tgt    = (const int*)d_in[1];
    const float* emb    = (const float*)d_in[2];
    const float* eW_ih0 = (const float*)d_in[3];
    const float* eW_hh0 = (const float*)d_in[4];
    const float* eb_ih0 = (const float*)d_in[5];
    const float* eb_hh0 = (const float*)d_in[6];
    const float* eW_ih1 = (const float*)d_in[7];
    const float* eW_hh1 = (const float*)d_in[8];
    const float* eb_ih1 = (const float*)d_in[9];
    const float* eb_hh1 = (const float*)d_in[10];
    const float* dW_ih0 = (const float*)d_in[11];
    const float* dW_hh0 = (const float*)d_in[12];
    const float* db_ih0 = (const float*)d_in[13];
    const float* db_hh0 = (const float*)d_in[14];
    const float* dW_ih1 = (const float*)d_in[15];
    const float* dW_hh1 = (const float*)d_in[16];
    const float* db_ih1 = (const float*)d_in[17];
    const float* db_hh1 = (const float*)d_in[18];
    const float* fcW    = (const float*)d_in[19];
    const float* fcb    = (const float*)d_in[20];
    float* out = (float*)d_out;

    // ---- workspace layout ----
    char* w = (char*)d_ws;
    size_t off = 0;
    auto walloc = [&](size_t bytes) { void* p = w + off; off += (bytes + 255) & ~(size_t)255; return p; };
    unsigned short* bW[8];
    const float* srcW[8] = {eW_ih0, eW_hh0, eW_ih1, eW_hh1, dW_ih0, dW_hh0, dW_ih1, dW_hh1};
    const int     szW[8] = {G4H*EE, G4H*HH, G4H*HH, G4H*HH, G4H*EE, G4H*HH, G4H*HH, G4H*HH};
    for (int i = 0; i < 8; ++i) bW[i] = (unsigned short*)walloc((size_t)szW[i] * 2);
    unsigned short* bfcW = (unsigned short*)walloc((size_t)VV * HH * 2);
    // zero region: h0a, h1a (bf16) + c0, c1 (fp32) — contiguous 24 MiB
    unsigned short* h0a = (unsigned short*)walloc((size_t)BB * HH * 2);
    unsigned short* h1a = (unsigned short*)walloc((size_t)BB * HH * 2);
    float* c0 = (float*)walloc((size_t)BB * HH * 4);
    float* c1 = (float*)walloc((size_t)BB * HH * 4);
    unsigned short* h0b = (unsigned short*)walloc((size_t)BB * HH * 2);
    unsigned short* h1b = (unsigned short*)walloc((size_t)BB * HH * 2);
    float* bsum = (float*)walloc((size_t)4 * G4H * 4);
    int*   toks = (int*)walloc((size_t)2 * SS * BB * 4);
    float* proj = (float*)walloc((size_t)2 * VV * G4H * 4);

    unsigned short* h0[2] = {h0a, h0b};
    unsigned short* h1[2] = {h1a, h1b};

    // ---- setup: packed weights (K=1024 only; W_ih0 via proj), biases, tokens ----
    for (int i = 0; i < 8; ++i) {
        if (i == 0 || i == 4) continue;               // eW_ih0/dW_ih0: replaced by proj tables
        cvt_pack_kernel<<<2048, 256, 0, stream>>>(srcW[i], bW[i]);
    }
    cvt_f2b_kernel<<<(VV * HH / 4 + 255) / 256, 256, 0, stream>>>(fcW, bfcW, VV * HH / 4);
    zero16_kernel<<<6144, 256, 0, stream>>>((uint4*)h0a);
    bias_sum_kernel<<<64, 256, 0, stream>>>(eb_ih0, eb_hh0, eb_ih1, eb_hh1,
                                            db_ih0, db_hh0, db_ih1, db_hh1, bsum);
    tok_kernel<<<384, 256, 0, stream>>>(src, tgt, toks);
    proj_kernel<<<2 * VV * 16, 256, 0, stream>>>(emb, eW_ih0, dW_ih0, proj);

    dim3 ggrid(G4H / 128, BB / 128);   // (32, 16) = 512 blocks = 2/CU

    int p = 0;
    for (int t = 0; t < 2 * SS; ++t) {
        const int enc = (t < SS);
        const unsigned short* Whh0 = enc ? bW[1] : bW[5];
        const unsigned short* Whh1 = enc ? bW[3] : bW[7];
        const unsigned short* Wih1 = enc ? bW[2] : bW[6];
        const float* b0 = bsum + (size_t)(enc ? 0 : 2) * G4H;
        const float* b1 = bsum + (size_t)(enc ? 1 : 3) * G4H;
        const float* pj = proj + (size_t)(enc ? 0 : 1) * VV * G4H;

        // L0: h0' = cell(h0 @ Whh0^T + proj[tok] + b0)   — 8 chunks (K=1024)
        lstm_step<<<ggrid, 256, 0, stream>>>(
            h0[p], Whh0, h0[p], Whh0, 8, b0, pj, toks + (size_t)t * BB, c0, h0[p ^ 1]);
        // L1: h1' = cell(h1 @ Whh1^T + h0' @ Wih1^T + b1) — 16 chunks (K=2048)
        lstm_step<<<ggrid, 256, 0, stream>>>(
            h1[p], Whh1, h0[p ^ 1], Wih1, 16, b1, nullptr, nullptr, c1, h1[p ^ 1]);
        if (!enc)
            fc_step_kernel<<<512, 256, 0, stream>>>(h1[p ^ 1], bfcW, fcb, out, t - SS);
        p ^= 1;
    }
}

// Round 12
// 3637.870 us; speedup vs baseline: 2.3286x; 1.2625x over previous
//
#include <hip/hip_runtime.h>

typedef __attribute__((ext_vector_type(8))) short short8;
typedef __attribute__((ext_vector_type(4))) float floatx4;

#define BB 2048   // batch
#define SS 24     // seq len (src and tgt)
#define HH 1024   // hidden
#define VV 37     // vocab
#define EE 256    // embed
#define G4H 4096  // 4*H gates
#define OSTR (SS * VV)   // out row stride = 888

__device__ __forceinline__ unsigned short f2bf(float f) {
    union { float f; unsigned u; } x; x.f = f;
    unsigned r = x.u + 0x7FFF + ((x.u >> 16) & 1);   // RNE
    return (unsigned short)(r >> 16);
}
__device__ __forceinline__ float bf2f(unsigned short s) {
    union { unsigned u; float f; } x; x.u = ((unsigned)s) << 16; return x.f;
}
__device__ __forceinline__ float sigm(float x) {
    x = fminf(fmaxf(x, -15.f), 15.f);
    return 1.f / (1.f + __expf(-x));
}
__device__ __forceinline__ float tanh_(float x) {
    x = fminf(fmaxf(x, -15.f), 15.f);
    float e = __expf(2.f * x);
    return (e - 1.f) / (e + 1.f);
}

// permuted W row C <- original row: gate g=(C>>4)&3 (i,f,g,o), unit u=(C>>6)*16+(C&15)
__device__ __forceinline__ int wrow_orig(int C) {
    return (((C >> 4) & 3) << 10) | ((C >> 6) << 4) | (C & 15);
}

// async global->LDS DMA, 16B/lane; LDS dest = wave-uniform base + lane*16 [m97/m104]
typedef const __attribute__((address_space(1))) void* gas_t;
typedef __attribute__((address_space(3))) void* las_t;
__device__ __forceinline__ void gl_lds16(const void* g, void* l) {
    __builtin_amdgcn_global_load_lds((gas_t)g, (las_t)l, 16, 0, 0);
}

// ------- fp32 -> bf16 packed-fragment layout for K=1024 weights -------
// Granule blk = ct*32 + kb (ct: 16-col tile, kb: 32-elem k-granule), 512 shorts each.
// packed[blk*512 + l*8 + e] = W[orig(ct*16 + (l&15))][kb*32 + (l>>4)*8 + e]
// => one wave-wide gl_lds of a granule reads 1 KB CONTIGUOUS, landing in LDS in
//    exactly the MFMA B-fragment layout.
__global__ __launch_bounds__(256)
void cvt_pack_kernel(const float* __restrict__ s, unsigned short* __restrict__ d) {
    int g = blockIdx.x * 256 + threadIdx.x;      // 4096*1024/8 = 524288 granule-slots
    int l   = g & 63;
    int blk = g >> 6;
    int kb  = blk & 31;
    int ct  = blk >> 5;
    int col = (ct << 4) + (l & 15);
    int k0  = (kb << 5) + ((l >> 4) << 3);
    const float* sp = s + (size_t)wrow_orig(col) * 1024 + k0;
    float4 v0 = *reinterpret_cast<const float4*>(sp);
    float4 v1 = *reinterpret_cast<const float4*>(sp + 4);
    ushort4 o0, o1;
    o0.x = f2bf(v0.x); o0.y = f2bf(v0.y); o0.z = f2bf(v0.z); o0.w = f2bf(v0.w);
    o1.x = f2bf(v1.x); o1.y = f2bf(v1.y); o1.z = f2bf(v1.z); o1.w = f2bf(v1.w);
    reinterpret_cast<ushort4*>(d)[(size_t)g * 2]     = o0;
    reinterpret_cast<ushort4*>(d)[(size_t)g * 2 + 1] = o1;
}

// ------- fcW (37x1024) -> packed B-granule layout, zero-padded to 48 cols -------
__global__ __launch_bounds__(256)
void cvt_fcw_kernel(const float* __restrict__ s, unsigned short* __restrict__ d) {
    int g = blockIdx.x * 256 + threadIdx.x;      // 48*1024/8 = 6144 granule-slots
    if (g >= 6144) return;
    int l   = g & 63;
    int blk = g >> 6;                            // 0..95 = ct*32 + kb
    int kb  = blk & 31;
    int ct  = blk >> 5;                          // 0..2
    int col = (ct << 4) + (l & 15);
    int k0  = (kb << 5) + ((l >> 4) << 3);
    ushort4 o0 = {0, 0, 0, 0}, o1 = {0, 0, 0, 0};
    if (col < VV) {
        const float* sp = s + (size_t)col * HH + k0;
        float4 v0 = *reinterpret_cast<const float4*>(sp);
        float4 v1 = *reinterpret_cast<const float4*>(sp + 4);
        o0.x = f2bf(v0.x); o0.y = f2bf(v0.y); o0.z = f2bf(v0.z); o0.w = f2bf(v0.w);
        o1.x = f2bf(v1.x); o1.y = f2bf(v1.y); o1.z = f2bf(v1.z); o1.w = f2bf(v1.w);
    }
    reinterpret_cast<ushort4*>(d)[(size_t)g * 2]     = o0;
    reinterpret_cast<ushort4*>(d)[(size_t)g * 2 + 1] = o1;
}

// ---------------- out init: out[b][t][v] = fcb[v] (atomic partials add onto it) ----
__global__ __launch_bounds__(256)
void out_init_kernel(const float* __restrict__ fcb, float* __restrict__ out, int n) {
    int i = blockIdx.x * 256 + threadIdx.x;
    if (i >= n) return;
    out[i] = fcb[i % VV];
}

// ---------------- zero init (h0a,h1a bf16 + c0,c1 fp32 region, 24 MiB) ----------------
__global__ __launch_bounds__(256) void zero16_kernel(uint4* __restrict__ p) {
    uint4 z; z.x = 0; z.y = 0; z.z = 0; z.w = 0;
    p[(size_t)blockIdx.x * 256 + threadIdx.x] = z;
}

// ---------------- token matrix [2,S,B] ----------------
__global__ __launch_bounds__(256)
void tok_kernel(const int* __restrict__ src, const int* __restrict__ tgt, int* __restrict__ toks) {
    int idx = blockIdx.x * 256 + threadIdx.x;   // 2*24*2048
    int b  = idx & 2047;
    int st = idx >> 11;
    int tok;
    if (st < SS) tok = src[b * SS + st];
    else { int t = st - SS; tok = (t == 0) ? 1 : tgt[b * SS + (t - 1)]; }
    toks[idx] = tok;
}

// ---------------- per-layer bias sums, permuted layout ----------------
__global__ __launch_bounds__(256) void bias_sum_kernel(
        const float* e0i, const float* e0h, const float* e1i, const float* e1h,
        const float* d0i, const float* d0h, const float* d1i, const float* d1h,
        float* __restrict__ out) {
    int idx = blockIdx.x * 256 + threadIdx.x;   // 4*4096
    int layer = idx >> 12, C = idx & 4095;
    int src_j = wrow_orig(C);
    const float* pi; const float* ph;
    switch (layer) {
        case 0:  pi = e0i; ph = e0h; break;
        case 1:  pi = e1i; ph = e1h; break;
        case 2:  pi = d0i; ph = d0h; break;
        default: pi = d1i; ph = d1h; break;
    }
    out[idx] = pi[src_j] + ph[src_j];
}

// ---------------- fp32 input-projection tables: proj[table][v][C] ----------------
__global__ __launch_bounds__(256)
void proj_kernel(const float* __restrict__ emb, const float* __restrict__ eWih,
                 const float* __restrict__ dWih, float* __restrict__ proj) {
    // grid = 2 tables * 37 v * 16 C-blocks = 1184
    int bid = blockIdx.x;
    int table = bid / (VV * 16);
    int rem   = bid - table * (VV * 16);
    int v     = rem >> 4;
    int cblk  = rem & 15;
    const float* W = table ? dWih : eWih;
    __shared__ float es[EE];
    es[threadIdx.x] = emb[v * EE + threadIdx.x];
    __syncthreads();
    int C = (cblk << 8) + threadIdx.x;
    const float* wr = W + (size_t)wrow_orig(C) * EE;
    float acc = 0.f;
#pragma unroll 8
    for (int k = 0; k < EE; ++k) acc += es[k] * wr[k];
    proj[((size_t)table * VV + v) * G4H + C] = acc;
}

// ---------------- LSTM step GEMM + cell (r11-verified, unchanged) ----------------
// gates[2048,4096] = A0 @ W0p^T (+ A1 @ W1p^T for 2nd half) + bias (+ proj[tok])
// h in A-fragment-granule layout; every gl_lds reads 1 KB contiguous. 64 KB LDS.
__global__ __launch_bounds__(256, 2)
void lstm_step(const unsigned short* __restrict__ A0, const unsigned short* __restrict__ W0,
               const unsigned short* __restrict__ A1, const unsigned short* __restrict__ W1,
               int nchunk,
               const float* __restrict__ bias, const float* __restrict__ prj,
               const int* __restrict__ tok,
               float* __restrict__ cst, unsigned short* __restrict__ hout)
{
    __shared__ __align__(16) unsigned short As[16384];  // 8 tiles x 4 kc x 512 = 32 KB
    __shared__ __align__(16) unsigned short Bs[16384];  // 32 KB

    const int tid  = threadIdx.x;
    const int lane = tid & 63;
    const int wave = tid >> 6;
    const int wm = wave >> 1, wn = wave & 1;
    const int m0 = blockIdx.y << 7;
    const int n0 = blockIdx.x << 7;

    const int r16 = lane & 15;
    const int rtb = m0 >> 4;                 // first of 8 16-row A tiles
    const int ctb = n0 >> 4;                 // first of 8 16-col W tiles
    const size_t wlane = (size_t)(lane << 3);

    floatx4 acc[4][4];
#pragma unroll
    for (int i = 0; i < 4; ++i)
#pragma unroll
        for (int j = 0; j < 4; ++j)
            acc[i][j] = (floatx4){0.f, 0.f, 0.f, 0.f};

    for (int t = 0; t < nchunk; ++t) {
        const unsigned short* Ap = (t & 8) ? A1 : A0;
        const unsigned short* Wp = (t & 8) ? W1 : W0;
        const int kb0 = (t & 7) << 2;             // granule base within segment
#pragma unroll
        for (int kc = 0; kc < 4; ++kc) {
            gl_lds16(Ap + (((size_t)((rtb + wave) << 5) + kb0 + kc) << 9) + wlane,
                     As + (wave << 11) + (kc << 9));
            gl_lds16(Ap + (((size_t)((rtb + wave + 4) << 5) + kb0 + kc) << 9) + wlane,
                     As + ((wave + 4) << 11) + (kc << 9));
            gl_lds16(Wp + (((size_t)((ctb + wave) << 5) + kb0 + kc) << 9) + wlane,
                     Bs + (wave << 11) + (kc << 9));
            gl_lds16(Wp + (((size_t)((ctb + wave + 4) << 5) + kb0 + kc) << 9) + wlane,
                     Bs + ((wave + 4) << 11) + (kc << 9));
        }
        __syncthreads();               // drains vmcnt(0): staged data visible to all waves

#pragma unroll
        for (int kc = 0; kc < 4; ++kc) {
            short8 af[4], bfr[4];
#pragma unroll
            for (int i = 0; i < 4; ++i) {
                af[i]  = *reinterpret_cast<const short8*>(As + ((((wm << 2) + i) << 11) + (kc << 9) + (lane << 3)));
                bfr[i] = *reinterpret_cast<const short8*>(Bs + ((((wn << 2) + i) << 11) + (kc << 9) + (lane << 3)));
            }
#pragma unroll
            for (int i = 0; i < 4; ++i)
#pragma unroll
                for (int j = 0; j < 4; ++j)
                    acc[i][j] = __builtin_amdgcn_mfma_f32_16x16x32_bf16(af[i], bfr[j], acc[i][j], 0, 0, 0);
        }
        __syncthreads();               // readers done before next chunk overwrites
    }

    // ---- in-register LSTM cell epilogue ----
    const int q = lane >> 4;
    const int ub = (((n0 >> 6) + wn) << 4) + r16;
    float bj[4];
#pragma unroll
    for (int j = 0; j < 4; ++j)
        bj[j] = bias[n0 + (wn << 6) + (j << 4) + r16];

    const int kbu = ub >> 5;
    const int lq  = ((ub & 31) >> 3) << 4;
    const int eu  = ub & 7;

#pragma unroll
    for (int i = 0; i < 4; ++i) {
#pragma unroll
        for (int p = 0; p < 4; ++p) {
            const int row = m0 + (wm << 6) + (i << 4) + (q << 2) + p;
            float g0 = acc[i][0][p] + bj[0];
            float g1 = acc[i][1][p] + bj[1];
            float g2 = acc[i][2][p] + bj[2];
            float g3 = acc[i][3][p] + bj[3];
            if (prj != nullptr) {
                const float* pr = prj + (size_t)tok[row] * G4H + n0 + (wn << 6) + r16;
                g0 += pr[0]; g1 += pr[16]; g2 += pr[32]; g3 += pr[48];
            }
            const float iv = sigm(g0);
            const float fv = sigm(g1);
            const float gv = tanh_(g2);
            const float ov = sigm(g3);
            const size_t ci = (size_t)row * HH + ub;          // c stays row-major
            const float cc = fv * cst[ci] + iv * gv;
            cst[ci] = cc;
            const size_t hi = ((((size_t)((row >> 4) << 5) + kbu) << 6) + lq + (q << 2) + p) * 8 + eu;
            hout[hi] = f2bf(ov * tanh_(cc));
        }
    }
}

// ---------------- FC head via MFMA, K-split (h1 packed-granule, fcW packed 48-col) ----
// grid (8 ksplit, 16 m-tiles). Block: 128 rows x 48 cols x K=128 slice; one stage+drain;
// 24 MFMA/wave; atomicAdd valid cols into out (pre-initialized with fcb).
__global__ __launch_bounds__(256, 2)
void fc_mfma_kernel(const unsigned short* __restrict__ h1p, const unsigned short* __restrict__ fcWp,
                    float* __restrict__ out, int t) {
    __shared__ __align__(16) unsigned short As[16384];  // 8 rt x 4 kc x 512 = 32 KB
    __shared__ __align__(16) unsigned short Bs[6144];   // 3 ct x 4 kc x 512 = 12 KB

    const int lane = threadIdx.x & 63;
    const int wave = threadIdx.x >> 6;
    const int ks = blockIdx.x;              // 0..7 k-split
    const int mb = blockIdx.y;              // 0..15 m-tile
    const int rtb = mb << 3;                // first 16-row granule tile
    const int kb0 = ks << 2;                // first 32-elem k-granule
    const size_t wlane = (size_t)(lane << 3);

    // stage A: row tiles (rtb+wave, rtb+wave+4) x kc 0..3
#pragma unroll
    for (int kc = 0; kc < 4; ++kc) {
        gl_lds16(h1p + (((size_t)((rtb + wave) << 5) + kb0 + kc) << 9) + wlane,
                 As + (wave << 11) + (kc << 9));
        gl_lds16(h1p + (((size_t)((rtb + wave + 4) << 5) + kb0 + kc) << 9) + wlane,
                 As + ((wave + 4) << 11) + (kc << 9));
    }
    // stage B: waves 0..2 each stage one 16-col tile x kc 0..3
    if (wave < 3) {
#pragma unroll
        for (int kc = 0; kc < 4; ++kc)
            gl_lds16(fcWp + (((size_t)(wave << 5) + kb0 + kc) << 9) + wlane,
                     Bs + (wave << 11) + (kc << 9));
    }
    __syncthreads();

    floatx4 acc[2][3];
#pragma unroll
    for (int i = 0; i < 2; ++i)
#pragma unroll
        for (int j = 0; j < 3; ++j)
            acc[i][j] = (floatx4){0.f, 0.f, 0.f, 0.f};

#pragma unroll
    for (int kc = 0; kc < 4; ++kc) {
        short8 af[2], bfr[3];
        af[0] = *reinterpret_cast<const short8*>(As + ((wave << 11) + (kc << 9) + (lane << 3)));
        af[1] = *reinterpret_cast<const short8*>(As + (((wave + 4) << 11) + (kc << 9) + (lane << 3)));
#pragma unroll
        for (int j = 0; j < 3; ++j)
            bfr[j] = *reinterpret_cast<const short8*>(Bs + ((j << 11) + (kc << 9) + (lane << 3)));
#pragma unroll
        for (int i = 0; i < 2; ++i)
#pragma unroll
            for (int j = 0; j < 3; ++j)
                acc[i][j] = __builtin_amdgcn_mfma_f32_16x16x32_bf16(af[i], bfr[j], acc[i][j], 0, 0, 0);
    }

    // epilogue: C frag col=lane&15, row=(lane>>4)*4+p  -> atomicAdd into out
    const int r16 = lane & 15, q = lane >> 4;
#pragma unroll
    for (int j = 0; j < 3; ++j) {
        const int col = (j << 4) + r16;
        if (col < VV) {
#pragma unroll
            for (int i = 0; i < 2; ++i) {
#pragma unroll
                for (int p = 0; p < 4; ++p) {
                    const int row = (mb << 7) + ((wave + (i << 2)) << 4) + (q << 2) + p;
                    atomicAdd(out + (size_t)row * OSTR + t * VV + col, acc[i][j][p]);
                }
            }
        }
    }
}

extern "C" void kernel_launch(void* const* d_in, const int* in_sizes, int n_in,
                              void* d_out, int out_size, void* d_ws, size_t ws_size,
                              hipStream_t stream) {
    const int*   src    = (const int*)d_in[0];
    const int*   tgt    = (const int*)d_in[1];
    const float* emb    = (const float*)d_in[2];
    const float* eW_ih0 = (const float*)d_in[3];
    const float* eW_hh0 = (const float*)d_in[4];
    const float* eb_ih0 = (const float*)d_in[5];
    const float* eb_hh0 = (const float*)d_in[6];
    const float* eW_ih1 = (const float*)d_in[7];
    const float* eW_hh1 = (const float*)d_in[8];
    const float* eb_ih1 = (const float*)d_in[9];
    const float* eb_hh1 = (const float*)d_in[10];
    const float* dW_ih0 = (const float*)d_in[11];
    const float* dW_hh0 = (const float*)d_in[12];
    const float* db_ih0 = (const float*)d_in[13];
    const float* db_hh0 = (const float*)d_in[14];
    const float* dW_ih1 = (const float*)d_in[15];
    const float* dW_hh1 = (const float*)d_in[16];
    const float* db_ih1 = (const float*)d_in[17];
    const float* db_hh1 = (const float*)d_in[18];
    const float* fcW    = (const float*)d_in[19];
    const float* fcb    = (const float*)d_in[20];
    float* out = (float*)d_out;

    // ---- workspace layout ----
    char* w = (char*)d_ws;
    size_t off = 0;
    auto walloc = [&](size_t bytes) { void* p = w + off; off += (bytes + 255) & ~(size_t)255; return p; };
    unsigned short* bW[8];
    const float* srcW[8] = {eW_ih0, eW_hh0, eW_ih1, eW_hh1, dW_ih0, dW_hh0, dW_ih1, dW_hh1};
    const int     szW[8] = {G4H*EE, G4H*HH, G4H*HH, G4H*HH, G4H*EE, G4H*HH, G4H*HH, G4H*HH};
    for (int i = 0; i < 8; ++i) bW[i] = (unsigned short*)walloc((size_t)szW[i] * 2);
    unsigned short* bfcWp = (unsigned short*)walloc((size_t)48 * HH * 2);   // packed, 48-col padded
    // zero region: h0a, h1a (bf16) + c0, c1 (fp32) — contiguous 24 MiB
    unsigned short* h0a = (unsigned short*)walloc((size_t)BB * HH * 2);
    unsigned short* h1a = (unsigned short*)walloc((size_t)BB * HH * 2);
    float* c0 = (float*)walloc((size_t)BB * HH * 4);
    float* c1 = (float*)walloc((size_t)BB * HH * 4);
    unsigned short* h0b = (unsigned short*)walloc((size_t)BB * HH * 2);
    unsigned short* h1b = (unsigned short*)walloc((size_t)BB * HH * 2);
    float* bsum = (float*)walloc((size_t)4 * G4H * 4);
    int*   toks = (int*)walloc((size_t)2 * SS * BB * 4);
    float* proj = (float*)walloc((size_t)2 * VV * G4H * 4);

    unsigned short* h0[2] = {h0a, h0b};
    unsigned short* h1[2] = {h1a, h1b};

    // ---- setup: packed weights (K=1024 only; W_ih0 via proj), fc, biases, tokens ----
    for (int i = 0; i < 8; ++i) {
        if (i == 0 || i == 4) continue;               // eW_ih0/dW_ih0: replaced by proj tables
        cvt_pack_kernel<<<2048, 256, 0, stream>>>(srcW[i], bW[i]);
    }
    cvt_fcw_kernel<<<24, 256, 0, stream>>>(fcW, bfcWp);
    out_init_kernel<<<(BB * OSTR + 255) / 256, 256, 0, stream>>>(fcb, out, BB * OSTR);
    zero16_kernel<<<6144, 256, 0, stream>>>((uint4*)h0a);
    bias_sum_kernel<<<64, 256, 0, stream>>>(eb_ih0, eb_hh0, eb_ih1, eb_hh1,
                                            db_ih0, db_hh0, db_ih1, db_hh1, bsum);
    tok_kernel<<<384, 256, 0, stream>>>(src, tgt, toks);
    proj_kernel<<<2 * VV * 16, 256, 0, stream>>>(emb, eW_ih0, dW_ih0, proj);

    dim3 ggrid(G4H / 128, BB / 128);   // (32, 16) = 512 blocks = 2/CU
    dim3 fgrid(8, 16);                 // (ksplit, m-tiles) = 128 blocks

    int p = 0;
    for (int t = 0; t < 2 * SS; ++t) {
        const int enc = (t < SS);
        const unsigned short* Whh0 = enc ? bW[1] : bW[5];
        const unsigned short* Whh1 = enc ? bW[3] : bW[7];
        const unsigned short* Wih1 = enc ? bW[2] : bW[6];
        const float* b0 = bsum + (size_t)(enc ? 0 : 2) * G4H;
        const float* b1 = bsum + (size_t)(enc ? 1 : 3) * G4H;
        const float* pj = proj + (size_t)(enc ? 0 : 1) * VV * G4H;

        // L0: h0' = cell(h0 @ Whh0^T + proj[tok] + b0)   — 8 chunks (K=1024)
        lstm_step<<<ggrid, 256, 0, stream>>>(
            h0[p], Whh0, h0[p], Whh0, 8, b0, pj, toks + (size_t)t * BB, c0, h0[p ^ 1]);
        // L1: h1' = cell(h1 @ Whh1^T + h0' @ Wih1^T + b1) — 16 chunks (K=2048)
        lstm_step<<<ggrid, 256, 0, stream>>>(
            h1[p], Whh1, h0[p ^ 1], Wih1, 16, b1, nullptr, nullptr, c1, h1[p ^ 1]);
        if (!enc)
            fc_mfma_kernel<<<fgrid, 256, 0, stream>>>(h1[p ^ 1], bfcWp, out, t - SS);
        p ^= 1;
    }
}